// Round 7
// baseline (172.941 us; speedup 1.0000x reference)
//
#include <hip/hip_runtime.h>
#include <hip/hip_cooperative_groups.h>

namespace cg = cooperative_groups;

// Problem constants (from reference):
//   B=8, V=6890, C=16, F=13776, FTOT=B*F=110208, H=W=512, K=1
//   npix = B*H*W*K = 2,097,152
// Output: int32 [B,H,W,K] = channel 0 of barycentric-interpolated
// per-vertex class features, truncated toward zero; 0 for background.
//
// Round 7: fuse prologue + main into ONE cooperative dispatch.
//   2048 blocks x 256 thr = 8192 waves = 32 waves/CU (full residency).
//   Phase 1: build 1.76 MB fa table (ch0 of each face's 3 verts).
//   grid.sync()
//   Phase 2: 4 px/thread grid-strided (coalesced per iteration, 4
//   independent gather chains per thread for MLP).
// Fallback: proven round-5 two-dispatch path if coop launch fails.

#define VC_C 16

typedef float vfloat4 __attribute__((ext_vector_type(4)));

__global__ void __launch_bounds__(256, 8)
fused_seg_kernel(const float* __restrict__ vc,
                 const int* __restrict__ faces,
                 const int* __restrict__ p2f,
                 const float* __restrict__ bary,
                 int* __restrict__ out,
                 float* __restrict__ fa_f,
                 int n3, int npix) {
    cg::grid_group grid = cg::this_grid();
    const int NT  = (int)(gridDim.x * blockDim.x);
    const int tid = (int)(blockIdx.x * blockDim.x + threadIdx.x);

    // Phase 1: one face-vertex per thread (n3 = 330624 < NT = 524288).
    for (int t = tid; t < n3; t += NT) {
        int f = t / 3;
        int j = t - 3 * f;
        int v = faces[t];
        fa_f[4 * f + j] = vc[(unsigned)v * VC_C];
    }

    grid.sync();

    const vfloat4* __restrict__ fa = (const vfloat4*)fa_f;

    // Phase 2: batches of 4 grid-strided pixels (npix == 4*NT here).
    int i = tid;
    for (; i + 3 * NT < npix; i += 4 * NT) {
        int i0 = i, i1 = i + NT, i2 = i + 2 * NT, i3 = i + 3 * NT;
        int f0 = p2f[i0], f1 = p2f[i1], f2 = p2f[i2], f3 = p2f[i3];
        vfloat4 a0 = fa[f0 >= 0 ? f0 : 0];
        vfloat4 a1 = fa[f1 >= 0 ? f1 : 0];
        vfloat4 a2 = fa[f2 >= 0 ? f2 : 0];
        vfloat4 a3 = fa[f3 >= 0 ? f3 : 0];
        float s0 = bary[3LL*i0+0]*a0.x + bary[3LL*i0+1]*a0.y + bary[3LL*i0+2]*a0.z;
        float s1 = bary[3LL*i1+0]*a1.x + bary[3LL*i1+1]*a1.y + bary[3LL*i1+2]*a1.z;
        float s2 = bary[3LL*i2+0]*a2.x + bary[3LL*i2+1]*a2.y + bary[3LL*i2+2]*a2.z;
        float s3 = bary[3LL*i3+0]*a3.x + bary[3LL*i3+1]*a3.y + bary[3LL*i3+2]*a3.z;
        out[i0] = f0 >= 0 ? (int)s0 : 0;  // trunc toward zero == astype(int32)
        out[i1] = f1 >= 0 ? (int)s1 : 0;
        out[i2] = f2 >= 0 ? (int)s2 : 0;
        out[i3] = f3 >= 0 ? (int)s3 : 0;
    }
    for (; i < npix; i += NT) {  // general tail (empty for this shape)
        int f = p2f[i];
        vfloat4 a = fa[f >= 0 ? f : 0];
        float s = bary[3LL*i+0]*a.x + bary[3LL*i+1]*a.y + bary[3LL*i+2]*a.z;
        out[i] = f >= 0 ? (int)s : 0;
    }
}

// ---- Fallback path (round-5 proven): two dispatches ----

__global__ void gather_face_attr_kernel(const float* __restrict__ vc,
                                        const int* __restrict__ faces,
                                        float* __restrict__ fa_f, int n3) {
    int t = blockIdx.x * blockDim.x + threadIdx.x;
    if (t >= n3) return;
    int f = t / 3;
    int j = t - 3 * f;
    int v = faces[t];
    fa_f[4 * f + j] = vc[(unsigned)v * VC_C];
}

__global__ void seg_shader_kernel(const vfloat4* __restrict__ fa,
                                  const int* __restrict__ p2f,
                                  const float* __restrict__ bary,
                                  int* __restrict__ out, int npix) {
    int i = blockIdx.x * blockDim.x + threadIdx.x;
    if (i >= npix) return;
    int f = p2f[i];
    float w0 = bary[3 * (long long)i + 0];
    float w1 = bary[3 * (long long)i + 1];
    float w2 = bary[3 * (long long)i + 2];
    vfloat4 a = fa[f >= 0 ? f : 0];
    float s = w0 * a.x + w1 * a.y + w2 * a.z;
    out[i] = f >= 0 ? (int)s : 0;
}

__global__ void seg_shader_direct_kernel(const float* __restrict__ vc,
                                         const int* __restrict__ faces,
                                         const int* __restrict__ p2f,
                                         const float* __restrict__ bary,
                                         int* __restrict__ out, int npix) {
    int i = blockIdx.x * blockDim.x + threadIdx.x;
    if (i >= npix) return;
    int f = p2f[i];
    int r = 0;
    if (f >= 0) {
        int v0 = faces[3 * f + 0];
        int v1 = faces[3 * f + 1];
        int v2 = faces[3 * f + 2];
        float w0 = bary[3 * (long long)i + 0];
        float w1 = bary[3 * (long long)i + 1];
        float w2 = bary[3 * (long long)i + 2];
        float s = w0 * vc[(long long)v0 * VC_C] +
                  w1 * vc[(long long)v1 * VC_C] +
                  w2 * vc[(long long)v2 * VC_C];
        r = (int)s;
    }
    out[i] = r;
}

extern "C" void kernel_launch(void* const* d_in, const int* in_sizes, int n_in,
                              void* d_out, int out_size, void* d_ws, size_t ws_size,
                              hipStream_t stream) {
    const float* verts_class = (const float*)d_in[0];   // [B*V*C] f32
    const int*   faces       = (const int*)d_in[1];     // [FTOT*3] i32
    const int*   pix_to_face = (const int*)d_in[2];     // [npix] i32
    const float* bary        = (const float*)d_in[3];   // [npix*3] f32
    int*         out         = (int*)d_out;             // [npix] i32

    const int ftot = in_sizes[1] / 3;
    const int npix = out_size;
    const size_t fa_bytes = (size_t)ftot * 4 * sizeof(float);

    if (d_ws != nullptr && ws_size >= fa_bytes) {
        float* fa_f = (float*)d_ws;
        int n3 = ftot * 3;

        // Try single-dispatch cooperative fusion first.
        const float* vc_a = verts_class;
        const int*   fc_a = faces;
        const int*   pf_a = pix_to_face;
        const float* by_a = bary;
        int*         ot_a = out;
        float*       fa_a = fa_f;
        int n3_a = n3, np_a = npix;
        void* args[] = {(void*)&vc_a, (void*)&fc_a, (void*)&pf_a, (void*)&by_a,
                        (void*)&ot_a, (void*)&fa_a, (void*)&n3_a, (void*)&np_a};
        hipError_t err = hipLaunchCooperativeKernel(
            reinterpret_cast<void*>(fused_seg_kernel),
            dim3(2048), dim3(256), args, 0, stream);
        if (err == hipSuccess) return;

        // Fallback: round-5 two-dispatch path.
        {
            int threads = 256;
            int blocks = (n3 + threads - 1) / threads;
            gather_face_attr_kernel<<<blocks, threads, 0, stream>>>(
                verts_class, faces, fa_f, n3);
        }
        {
            int threads = 256;
            int blocks = (npix + threads - 1) / threads;
            seg_shader_kernel<<<blocks, threads, 0, stream>>>(
                (const vfloat4*)fa_f, pix_to_face, bary, out, npix);
        }
    } else {
        int threads = 256;
        int blocks = (npix + threads - 1) / threads;
        seg_shader_direct_kernel<<<blocks, threads, 0, stream>>>(
            verts_class, faces, pix_to_face, bary, out, npix);
    }
}

// Round 8
// 25.689 us; speedup vs baseline: 6.7321x; 6.7321x over previous
//
#include <hip/hip_runtime.h>

// Problem constants (from reference):
//   B=8, V=6890, C=16, F=13776, FTOT=B*F=110208, H=W=512, K=1
//   npix = B*H*W*K = 2,097,152
// Output: int32 [B,H,W,K] = channel 0 of barycentric-interpolated
// per-vertex class features, truncated toward zero; 0 for background.
//
// Round 8: R5 two-dispatch structure. Main kernel = 2 px/thread
// (1,048,576 threads = 16384 waves = full 32/CU residency x2), giving
// MLP=2 independent gather chains at full occupancy (R5 was MLP=1 @ 4
// residencies; R1 was MLP=4 @ 1 residency; this is the untested middle).
// Prologue = one thread per FACE (3 gathers, one float4 store).

#define VC_C 16

typedef float vfloat4 __attribute__((ext_vector_type(4)));

// Kernel 1: one thread per face; 3 independent ch0 gathers, 1 float4 store.
__global__ void gather_face_attr_kernel(const float* __restrict__ vc,
                                        const int* __restrict__ faces,
                                        vfloat4* __restrict__ fa, int ftot) {
    int f = blockIdx.x * blockDim.x + threadIdx.x;
    if (f >= ftot) return;
    int v0 = faces[3 * f + 0];
    int v1 = faces[3 * f + 1];
    int v2 = faces[3 * f + 2];
    vfloat4 a = {vc[(unsigned)v0 * VC_C], vc[(unsigned)v1 * VC_C],
                 vc[(unsigned)v2 * VC_C], 0.0f};
    fa[f] = a;
}

// Kernel 2: 2 pixels per thread, strided by total thread count so every
// load/store stays perfectly coalesced; 2 independent gather chains.
__global__ void __launch_bounds__(256, 8)
seg_shader_kernel(const vfloat4* __restrict__ fa,
                  const int* __restrict__ p2f,
                  const float* __restrict__ bary,
                  int* __restrict__ out, int half) {
    int i0 = blockIdx.x * blockDim.x + threadIdx.x;
    if (i0 >= half) return;
    int i1 = i0 + half;

    int f0 = p2f[i0];
    int f1 = p2f[i1];

    float w00 = bary[3 * (long long)i0 + 0];
    float w01 = bary[3 * (long long)i0 + 1];
    float w02 = bary[3 * (long long)i0 + 2];
    float w10 = bary[3 * (long long)i1 + 0];
    float w11 = bary[3 * (long long)i1 + 1];
    float w12 = bary[3 * (long long)i1 + 2];

    vfloat4 a0 = fa[f0 >= 0 ? f0 : 0];
    vfloat4 a1 = fa[f1 >= 0 ? f1 : 0];

    float s0 = w00 * a0.x + w01 * a0.y + w02 * a0.z;
    float s1 = w10 * a1.x + w11 * a1.y + w12 * a1.z;

    out[i0] = f0 >= 0 ? (int)s0 : 0;  // trunc toward zero == astype(int32)
    out[i1] = f1 >= 0 ? (int)s1 : 0;
}

// Fallback (no workspace): direct gathers, 1 pixel per thread.
__global__ void seg_shader_direct_kernel(const float* __restrict__ vc,
                                         const int* __restrict__ faces,
                                         const int* __restrict__ p2f,
                                         const float* __restrict__ bary,
                                         int* __restrict__ out, int npix) {
    int i = blockIdx.x * blockDim.x + threadIdx.x;
    if (i >= npix) return;
    int f = p2f[i];
    int r = 0;
    if (f >= 0) {
        int v0 = faces[3 * f + 0];
        int v1 = faces[3 * f + 1];
        int v2 = faces[3 * f + 2];
        float w0 = bary[3 * (long long)i + 0];
        float w1 = bary[3 * (long long)i + 1];
        float w2 = bary[3 * (long long)i + 2];
        float s = w0 * vc[(long long)v0 * VC_C] +
                  w1 * vc[(long long)v1 * VC_C] +
                  w2 * vc[(long long)v2 * VC_C];
        r = (int)s;
    }
    out[i] = r;
}

extern "C" void kernel_launch(void* const* d_in, const int* in_sizes, int n_in,
                              void* d_out, int out_size, void* d_ws, size_t ws_size,
                              hipStream_t stream) {
    const float* verts_class = (const float*)d_in[0];   // [B*V*C] f32
    const int*   faces       = (const int*)d_in[1];     // [FTOT*3] i32
    const int*   pix_to_face = (const int*)d_in[2];     // [npix] i32
    const float* bary        = (const float*)d_in[3];   // [npix*3] f32
    int*         out         = (int*)d_out;             // [npix] i32

    const int ftot = in_sizes[1] / 3;
    const int npix = out_size;
    const size_t fa_bytes = (size_t)ftot * 4 * sizeof(float);

    if (d_ws != nullptr && ws_size >= fa_bytes && (npix % 2) == 0) {
        vfloat4* fa = (vfloat4*)d_ws;
        {
            int threads = 256;
            int blocks = (ftot + threads - 1) / threads;
            gather_face_attr_kernel<<<blocks, threads, 0, stream>>>(
                verts_class, faces, fa, ftot);
        }
        {
            int half = npix / 2;
            int threads = 256;
            int blocks = (half + threads - 1) / threads;
            seg_shader_kernel<<<blocks, threads, 0, stream>>>(
                fa, pix_to_face, bary, out, half);
        }
    } else {
        int threads = 256;
        int blocks = (npix + threads - 1) / threads;
        seg_shader_direct_kernel<<<blocks, threads, 0, stream>>>(
            verts_class, faces, pix_to_face, bary, out, npix);
    }
}